// Round 5
// baseline (300.656 us; speedup 1.0000x reference)
//
#include <hip/hip_runtime.h>

typedef short short8 __attribute__((ext_vector_type(8)));
typedef int   intx8  __attribute__((ext_vector_type(8)));
typedef float floatx16 __attribute__((ext_vector_type(16)));

#define AS_G __attribute__((address_space(1)))
#define AS_L __attribute__((address_space(3)))

__device__ __forceinline__ unsigned short f2bf(float f) {
    union { float f; unsigned u; } v; v.f = f;
    unsigned r = (v.u + 0x7FFF + ((v.u >> 16) & 1)) >> 16;
    return (unsigned short)r;
}
__device__ __forceinline__ float dec8f(int c) {   // E4M3, NaN code -> 480 (like ref)
    float s = (c & 128) ? -1.f : 1.f;
    int e = (c >> 3) & 15, m = c & 7;
    float mag = e ? ldexpf(1.f + 0.125f * (float)m, e - 7) : ldexpf(0.125f * (float)m, -6);
    return s * mag;
}

// ---- prepass: unified code rows [fp4 1536B | fp6(6-bit) 576B | fp8->bf16 512B], stride 2624.
// ---- St[it][row] dwords: it<24 = fp4 scale quads; it in [24,36) = fp6 scale pairs (bytes 0,1).
__global__ __launch_bounds__(256) void pack_side(
    const int* __restrict__ Pn, const int* __restrict__ Ps, const int* __restrict__ Po,
    const int* __restrict__ Sn, const int* __restrict__ Ss, const int* __restrict__ So,
    unsigned char* __restrict__ Cc, unsigned char* __restrict__ St, int R)
{
    int t = blockIdx.x * 256 + threadIdx.x;
    int T0 = R * 96;           // fp4 pack, 16B/thread
    int T1 = T0 + R * 36;      // fp6 byte-pack, 16B/thread
    int T2 = T1 + R * 32;      // fp8 -> scaled bf16, 8 vals (16B)/thread
    int T3 = T2 + R * 24;      // fp4 scale quads
    int T4 = T3 + R * 12;      // fp6 scale pairs
    if (t < T0) {
        int r = t / 96, j = t - r * 96;
        const int4* p = (const int4*)(Pn + (size_t)r * 1536 + j * 16);
        uint4 o; unsigned* po = (unsigned*)&o;
        #pragma unroll
        for (int q = 0; q < 4; q++) {
            int4 b = p[q];
            po[q] = (b.x & 255) | ((b.y & 255) << 8) | ((b.z & 255) << 16) | ((unsigned)(b.w & 255) << 24);
        }
        *(uint4*)(Cc + (size_t)r * 2624 + j * 16) = o;
    } else if (t < T1) {
        t -= T0; int r = t / 36, j = t - r * 36;
        const int4* p = (const int4*)(Ps + (size_t)r * 576 + j * 16);
        uint4 o; unsigned* po = (unsigned*)&o;
        #pragma unroll
        for (int q = 0; q < 4; q++) {
            int4 b = p[q];
            po[q] = (b.x & 255) | ((b.y & 255) << 8) | ((b.z & 255) << 16) | ((unsigned)(b.w & 255) << 24);
        }
        *(uint4*)(Cc + (size_t)r * 2624 + 1536 + j * 16) = o;
    } else if (t < T2) {
        t -= T1; int r = t / 32, j = t - r * 32;
        const int4* p = (const int4*)(Po + (size_t)r * 256 + j * 8);
        int4 c0 = p[0], c1 = p[1];
        int e = So[r * 8 + (j >> 2)] - 127;
        int cs[8] = { c0.x, c0.y, c0.z, c0.w, c1.x, c1.y, c1.z, c1.w };
        uint4 o; unsigned* po = (unsigned*)&o;
        #pragma unroll
        for (int i = 0; i < 4; i++) {
            unsigned lo = f2bf(ldexpf(dec8f(cs[2 * i] & 255), e));
            unsigned hi = f2bf(ldexpf(dec8f(cs[2 * i + 1] & 255), e));
            po[i] = lo | (hi << 16);
        }
        *(uint4*)(Cc + (size_t)r * 2624 + 2112 + j * 16) = o;
    } else if (t < T3) {
        t -= T2; int r = t / 24, q = t - r * 24;
        int4 v = *(const int4*)(Sn + (size_t)r * 96 + q * 4);
        unsigned o = (v.x & 255) | ((v.y & 255) << 8) | ((v.z & 255) << 16) | ((unsigned)(v.w & 255) << 24);
        *(unsigned*)(St + ((size_t)q * R + r) * 4) = o;
    } else if (t < T4) {
        t -= T3; int r = t / 12, b2 = t - r * 12;
        int s0 = Ss[(size_t)r * 24 + 2 * b2] & 255, s1 = Ss[(size_t)r * 24 + 2 * b2 + 1] & 255;
        *(unsigned*)(St + ((size_t)(24 + b2) * R + r) * 4) = (unsigned)(s0 | (s1 << 8));
    }
}

// ---- unified GEMM: 44 iters (24 fp4 fmt4 + 12 fp6 fmt3 + 8 bf16), dbuf LDS, 1 barrier/iter,
// ---- register-pipelined scales. 128x128 tile, 4 waves, 2x2 of 32x32 accumulators.
__global__ __launch_bounds__(256, 3) void gemm_mx(
    const unsigned char* __restrict__ Ac, const unsigned char* __restrict__ Bc,
    const unsigned char* __restrict__ SaT, const unsigned char* __restrict__ SbT,
    const float* __restrict__ bias, float* __restrict__ C, int M, int N)
{
    __shared__ __align__(16) unsigned char sA[2][8192];
    __shared__ __align__(16) unsigned char sB[2][8192];

    int tid = threadIdx.x, w = tid >> 6, l = tid & 63;
    int bm = blockIdx.y, bn = blockIdx.x;
    int wm = (w >> 1) * 64, wn = (w & 1) * 64;
    int lr = l & 31, lh = l >> 5;

    floatx16 acc[2][2] = {};

    int rgA[2] = { bm * 128 + wm + lr, bm * 128 + wm + 32 + lr };
    int cgB[2] = { bn * 128 + wn + lr, bn * 128 + wn + 32 + lr };

    // staging: chunk c = j*256 + w*64 + l; sub = c>>7, row = c&127; LDS k-major sub*2048 + row*16.
    int c0 = w * 64 + l;
    int sub0 = c0 >> 7, row0 = c0 & 127;
    int c1 = 256 + w * 64 + l;
    int sub1 = c1 >> 7, row1 = c1 & 127;
    const unsigned char* agp0 = Ac + (size_t)(bm * 128 + row0) * 2624 + sub0 * 16;
    const unsigned char* agp1 = Ac + (size_t)(bm * 128 + row1) * 2624 + sub1 * 16;
    const unsigned char* bgp0 = Bc + (size_t)(bn * 128 + row0) * 2624 + sub0 * 16;
    const unsigned char* bgp1 = Bc + (size_t)(bn * 128 + row1) * 2624 + sub1 * 16;
    int ldsoff0 = (w * 64) * 16, ldsoff1 = (256 + w * 64) * 16;

    auto stage = [&](int it, int p) {
        int off = it < 24 ? it * 64 : (it < 36 ? 1536 + (it - 24) * 48 : 2112 + (it - 36) * 64);
        __builtin_amdgcn_global_load_lds((const AS_G void*)(agp0 + off), (AS_L void*)(sA[p] + ldsoff0), 16, 0, 0);
        __builtin_amdgcn_global_load_lds((const AS_G void*)(bgp0 + off), (AS_L void*)(sB[p] + ldsoff0), 16, 0, 0);
        if (!(it >= 24 && it < 36 && w >= 2)) {      // 48B iters: sub 3 (waves 2,3's chunk1) not staged
            __builtin_amdgcn_global_load_lds((const AS_G void*)(agp1 + off), (AS_L void*)(sA[p] + ldsoff1), 16, 0, 0);
            __builtin_amdgcn_global_load_lds((const AS_G void*)(bgp1 + off), (AS_L void*)(sB[p] + ldsoff1), 16, 0, 0);
        }
    };
    auto ldsc = [&](int it, unsigned sc[4]) {
        sc[0] = *(const unsigned*)(SaT + ((size_t)it * M + rgA[0]) * 4);
        sc[1] = *(const unsigned*)(SaT + ((size_t)it * M + rgA[1]) * 4);
        sc[2] = *(const unsigned*)(SbT + ((size_t)it * N + cgB[0]) * 4);
        sc[3] = *(const unsigned*)(SbT + ((size_t)it * N + cgB[1]) * 4);
    };

    unsigned sc[4], scn[4];
    stage(0, 0);
    ldsc(0, sc);
    __syncthreads();

    for (int it = 0; it < 44; ++it) {
        int p = it & 1;
        if (it < 43) {
            stage(it + 1, 1 - p);
            if (it + 1 < 36) ldsc(it + 1, scn);
        }

        const unsigned char* sAp = sA[p];
        const unsigned char* sBp = sB[p];

        if (it < 24) {
            // fp4 (fmt 4, round-3-validated): two K=64 steps; lane = 16B = one 32-k scale block
            #pragma unroll
            for (int s = 0; s < 2; s++) {
                int s2 = s * 2 + lh;
                int shift = 8 * s2;
                intx8 af[2], bf2[2];
                #pragma unroll
                for (int i = 0; i < 2; i++) {
                    int4 v = *(const int4*)(sAp + s2 * 2048 + (wm + i * 32 + lr) * 16);
                    af[i] = (intx8){ v.x, v.y, v.z, v.w, 0, 0, 0, 0 };
                }
                #pragma unroll
                for (int j = 0; j < 2; j++) {
                    int4 v = *(const int4*)(sBp + s2 * 2048 + (wn + j * 32 + lr) * 16);
                    bf2[j] = (intx8){ v.x, v.y, v.z, v.w, 0, 0, 0, 0 };
                }
                #pragma unroll
                for (int i = 0; i < 2; i++)
                    #pragma unroll
                    for (int j = 0; j < 2; j++)
                        acc[i][j] = __builtin_amdgcn_mfma_scale_f32_32x32x64_f8f6f4(
                            af[i], bf2[j], acc[i][j], 4, 4,
                            0, (int)((sc[i] >> shift) & 255),
                            0, (int)((sc[2 + j] >> shift) & 255));
            }
        } else if (it < 36) {
            // fp6 (fmt 3, round-3-validated u/v assembly): one K=64 step, 24B/lane
            int shift = 8 * lh;
            intx8 af[2], bf2[2];
            #pragma unroll
            for (int i = 0; i < 2; i++) {
                int r16 = (wm + i * 32 + lr) * 16;
                int4 v = *(const int4*)(sAp + lh * 4096 + r16);
                int2 u = *(const int2*)(sAp + 2048 + r16 + lh * 8);
                af[i] = (intx8){ lh ? u.x : v.x, lh ? u.y : v.y, lh ? v.x : v.z,
                                 lh ? v.y : v.w, lh ? v.z : u.x, lh ? v.w : u.y, 0, 0 };
            }
            #pragma unroll
            for (int j = 0; j < 2; j++) {
                int r16 = (wn + j * 32 + lr) * 16;
                int4 v = *(const int4*)(sBp + lh * 4096 + r16);
                int2 u = *(const int2*)(sBp + 2048 + r16 + lh * 8);
                bf2[j] = (intx8){ lh ? u.x : v.x, lh ? u.y : v.y, lh ? v.x : v.z,
                                  lh ? v.y : v.w, lh ? v.z : u.x, lh ? v.w : u.y, 0, 0 };
            }
            #pragma unroll
            for (int i = 0; i < 2; i++)
                #pragma unroll
                for (int j = 0; j < 2; j++)
                    acc[i][j] = __builtin_amdgcn_mfma_scale_f32_32x32x64_f8f6f4(
                        af[i], bf2[j], acc[i][j], 3, 3,
                        0, (int)((sc[i] >> shift) & 255),
                        0, (int)((sc[2 + j] >> shift) & 255));
        } else {
            // fp8-as-bf16 (round-3-validated): two K=16 bf16 MFMAs over the 64B window
            #pragma unroll
            for (int s = 0; s < 2; s++) {
                int kb16 = s * 2 + lh;
                short8 af[2], bf2[2];
                #pragma unroll
                for (int i = 0; i < 2; i++)
                    af[i] = *(const short8*)(sAp + kb16 * 2048 + (wm + i * 32 + lr) * 16);
                #pragma unroll
                for (int j = 0; j < 2; j++)
                    bf2[j] = *(const short8*)(sBp + kb16 * 2048 + (wn + j * 32 + lr) * 16);
                #pragma unroll
                for (int i = 0; i < 2; i++)
                    #pragma unroll
                    for (int j = 0; j < 2; j++)
                        acc[i][j] = __builtin_amdgcn_mfma_f32_32x32x16_bf16(af[i], bf2[j], acc[i][j], 0, 0, 0);
            }
        }

        if (it < 43) {
            #pragma unroll
            for (int q = 0; q < 4; q++) sc[q] = scn[q];
        }
        __syncthreads();
    }

    // epilogue: 32x32 C/D layout col=lane&31, row=(r&3)+8*(r>>2)+4*lh (m74/m101-verified)
    #pragma unroll
    for (int i = 0; i < 2; i++)
        #pragma unroll
        for (int j = 0; j < 2; j++) {
            int col = bn * 128 + wn + j * 32 + lr;
            float bv = bias[col];
            #pragma unroll
            for (int r = 0; r < 16; r++) {
                int row = bm * 128 + wm + i * 32 + (r & 3) + 8 * (r >> 2) + 4 * lh;
                C[(size_t)row * N + col] = acc[i][j][r] + bv;
            }
        }
}

extern "C" void kernel_launch(void* const* d_in, const int* in_sizes, int n_in,
                              void* d_out, int out_size, void* d_ws, size_t ws_size,
                              hipStream_t stream) {
    const int* AN   = (const int*)d_in[0];
    const int* ASs  = (const int*)d_in[1];
    const int* AO   = (const int*)d_in[2];
    const int* SFAN = (const int*)d_in[3];
    const int* SFAS = (const int*)d_in[4];
    const int* SFAO = (const int*)d_in[5];
    const int* BN   = (const int*)d_in[6];
    const int* BS   = (const int*)d_in[7];
    const int* BO   = (const int*)d_in[8];
    const int* SFBN = (const int*)d_in[9];
    const int* SFBS = (const int*)d_in[10];
    const int* SFBO = (const int*)d_in[11];
    const float* bias = (const float*)d_in[12];

    int M = in_sizes[0] / 1536;
    int N = in_sizes[6] / 1536;

    unsigned char* ws = (unsigned char*)d_ws;
    size_t o = 0;
    unsigned char* Acod = ws + o;  o += (size_t)M * 2624;
    unsigned char* Bcod = ws + o;  o += (size_t)N * 2624;
    unsigned char* SaT  = ws + o;  o += (size_t)36 * M * 4;
    unsigned char* SbT  = ws + o;  o += (size_t)36 * N * 4;

    int TA = M * 200, TB = N * 200;
    pack_side<<<(TA + 255) / 256, 256, 0, stream>>>(AN, ASs, AO, SFAN, SFAS, SFAO, Acod, SaT, M);
    pack_side<<<(TB + 255) / 256, 256, 0, stream>>>(BN, BS, BO, SFBN, SFBS, SFBO, Bcod, SbT, N);

    dim3 grid(N / 128, M / 128);
    gemm_mx<<<grid, 256, 0, stream>>>(Acod, Bcod, SaT, SbT, bias, (float*)d_out, M, N);
}

// Round 6
// 228.602 us; speedup vs baseline: 1.3152x; 1.3152x over previous
//
#include <hip/hip_runtime.h>

typedef short short8 __attribute__((ext_vector_type(8)));
typedef int   intx8  __attribute__((ext_vector_type(8)));
typedef float floatx16 __attribute__((ext_vector_type(16)));

__device__ __forceinline__ unsigned short f2bf(float f) {
    union { float f; unsigned u; } v; v.f = f;
    unsigned r = (v.u + 0x7FFF + ((v.u >> 16) & 1)) >> 16;
    return (unsigned short)r;
}
__device__ __forceinline__ float dec8f(int c) {   // E4M3, NaN code -> 480 (like ref)
    float s = (c & 128) ? -1.f : 1.f;
    int e = (c >> 3) & 15, m = c & 7;
    float mag = e ? ldexpf(1.f + 0.125f * (float)m, e - 7) : ldexpf(0.125f * (float)m, -6);
    return s * mag;
}
__device__ __forceinline__ unsigned pk4(int a, int b, int c, int d) {
    return (a & 255) | ((b & 255) << 8) | ((c & 255) << 16) | ((unsigned)(d & 255) << 24);
}

// ---- prepass (per side): k-major repack so GEMM fragment loads are coalesced.
// C4 [96][R][16]  : fp4 codes, 16B chunk j = k nibbles 32j..32j+31
// C6 [24][R][24]  : fp6 raw 6-bit stream, 24B window g = k 32g..32g+31 (per-lane operand halves)
// C8 [32][R][8]   : fp8 decoded+scaled to bf16, 16B chunk j = k 8j..8j+7
// St [36][R][4]   : rows 0..23 fp4 scale quads (byte i = block 4q+i); rows 24..35 fp6 pairs
__global__ __launch_bounds__(256) void pack_side(
    const int* __restrict__ Pn, const int* __restrict__ Ps, const int* __restrict__ Po,
    const int* __restrict__ Sn, const int* __restrict__ Ss, const int* __restrict__ So,
    unsigned char* __restrict__ C4, unsigned char* __restrict__ C6,
    unsigned short* __restrict__ C8, unsigned char* __restrict__ St, int R)
{
    int t = blockIdx.x * 256 + threadIdx.x;
    int T0 = R * 96, T1 = T0 + R * 24, T2 = T1 + R * 32, T3 = T2 + R * 24, T4 = T3 + R * 12;
    if (t < T0) {                                  // fp4: 16 B from 16 int32
        int j = t / R, r = t - j * R;
        const int4* p = (const int4*)(Pn + (size_t)r * 1536 + j * 16);
        uint4 o; unsigned* po = (unsigned*)&o;
        #pragma unroll
        for (int q = 0; q < 4; q++) { int4 b = p[q]; po[q] = pk4(b.x, b.y, b.z, b.w); }
        *(uint4*)(C4 + ((size_t)j * R + r) * 16) = o;
    } else if (t < T1) {                           // fp6: 24 B window from 24 int32
        t -= T0; int g = t / R, r = t - g * R;
        const int4* p = (const int4*)(Ps + (size_t)r * 576 + g * 24);
        unsigned d[6];
        #pragma unroll
        for (int q = 0; q < 6; q++) { int4 b = p[q]; d[q] = pk4(b.x, b.y, b.z, b.w); }
        unsigned char* dst = C6 + ((size_t)g * R + r) * 24;
        *(int2*)(dst)      = (int2){ (int)d[0], (int)d[1] };
        *(int2*)(dst + 8)  = (int2){ (int)d[2], (int)d[3] };
        *(int2*)(dst + 16) = (int2){ (int)d[4], (int)d[5] };
    } else if (t < T2) {                           // fp8 -> scaled bf16, 8 vals
        t -= T1; int j = t / R, r = t - j * R;
        const int4* p = (const int4*)(Po + (size_t)r * 256 + j * 8);
        int4 c0 = p[0], c1 = p[1];
        int e = So[r * 8 + (j >> 2)] - 127;
        int cs[8] = { c0.x, c0.y, c0.z, c0.w, c1.x, c1.y, c1.z, c1.w };
        uint4 o; unsigned* po = (unsigned*)&o;
        #pragma unroll
        for (int i = 0; i < 4; i++) {
            unsigned lo = f2bf(ldexpf(dec8f(cs[2 * i] & 255), e));
            unsigned hi = f2bf(ldexpf(dec8f(cs[2 * i + 1] & 255), e));
            po[i] = lo | (hi << 16);
        }
        *(uint4*)((unsigned char*)C8 + ((size_t)j * R + r) * 16) = o;
    } else if (t < T3) {                           // fp4 scale quads
        t -= T2; int q = t / R, r = t - q * R;
        int4 v = *(const int4*)(Sn + (size_t)r * 96 + q * 4);
        *(unsigned*)(St + ((size_t)q * R + r) * 4) = pk4(v.x, v.y, v.z, v.w);
    } else if (t < T4) {                           // fp6 scale pairs
        t -= T3; int b2 = t / R, r = t - b2 * R;
        int s0 = Ss[(size_t)r * 24 + 2 * b2] & 255, s1 = Ss[(size_t)r * 24 + 2 * b2 + 1] & 255;
        *(unsigned*)(St + ((size_t)(24 + b2) * R + r) * 4) = (unsigned)(s0 | (s1 << 8));
    }
}

// ---- barrier-free direct-load MX GEMM. 128x128 block, 4 waves, 2x2 of 32x32 acc/wave.
// All fragment loads are coalesced global_load_dwordx4 from k-major arrays; no LDS, no
// __syncthreads -> compiler pipelines with fine-grained vmcnt(N). Formats: fp4 fmt4 +
// fp6 fmt3 (r3/r5-validated mappings, per-lane-half 32-k blocks + scale byte), fp8 as bf16.
__global__ __launch_bounds__(256, 2) void gemm_mx(
    const unsigned char* __restrict__ A4, const unsigned char* __restrict__ B4,
    const unsigned char* __restrict__ A6, const unsigned char* __restrict__ B6,
    const unsigned short* __restrict__ A8, const unsigned short* __restrict__ B8,
    const unsigned char* __restrict__ SaT, const unsigned char* __restrict__ SbT,
    const float* __restrict__ bias, float* __restrict__ C, int M, int N)
{
    int tid = threadIdx.x, w = tid >> 6, l = tid & 63;
    int bm = blockIdx.y, bn = blockIdx.x;
    int wm = (w >> 1) * 64, wn = (w & 1) * 64;
    int lr = l & 31, lh = l >> 5;

    floatx16 acc[2][2] = {};

    int rA[2] = { bm * 128 + wm + lr, bm * 128 + wm + 32 + lr };
    int cB[2] = { bn * 128 + wn + lr, bn * 128 + wn + 32 + lr };

    // ================= fp4 (fmt 4): 48 steps of K=64 =================
    {
        unsigned offA[2] = { ((unsigned)lh * M + rA[0]) * 16u, ((unsigned)lh * M + rA[1]) * 16u };
        unsigned offB[2] = { ((unsigned)lh * N + cB[0]) * 16u, ((unsigned)lh * N + cB[1]) * 16u };
        unsigned strA = 32u * (unsigned)M, strB = 32u * (unsigned)N;
        #pragma unroll 2
        for (int up = 0; up < 24; ++up) {
            unsigned sca0 = *(const unsigned*)(SaT + ((size_t)up * M + rA[0]) * 4);
            unsigned sca1 = *(const unsigned*)(SaT + ((size_t)up * M + rA[1]) * 4);
            unsigned scb0 = *(const unsigned*)(SbT + ((size_t)up * N + cB[0]) * 4);
            unsigned scb1 = *(const unsigned*)(SbT + ((size_t)up * N + cB[1]) * 4);
            #pragma unroll
            for (int s = 0; s < 2; ++s) {
                unsigned u = (unsigned)(up * 2 + s);
                intx8 af[2], bfr[2];
                #pragma unroll
                for (int i = 0; i < 2; i++) {
                    int4 v = *(const int4*)(A4 + offA[i] + (size_t)u * strA);
                    af[i] = (intx8){ v.x, v.y, v.z, v.w, 0, 0, 0, 0 };
                }
                #pragma unroll
                for (int j = 0; j < 2; j++) {
                    int4 v = *(const int4*)(B4 + offB[j] + (size_t)u * strB);
                    bfr[j] = (intx8){ v.x, v.y, v.z, v.w, 0, 0, 0, 0 };
                }
                int sh = 8 * (s * 2 + lh);
                int sa[2] = { (int)((sca0 >> sh) & 255), (int)((sca1 >> sh) & 255) };
                int sb[2] = { (int)((scb0 >> sh) & 255), (int)((scb1 >> sh) & 255) };
                #pragma unroll
                for (int i = 0; i < 2; i++)
                    #pragma unroll
                    for (int j = 0; j < 2; j++)
                        acc[i][j] = __builtin_amdgcn_mfma_scale_f32_32x32x64_f8f6f4(
                            af[i], bfr[j], acc[i][j], 4, 4, 0, sa[i], 0, sb[j]);
            }
        }
    }

    // ================= fp6 (fmt 3): 12 steps of K=64 =================
    {
        #pragma unroll 2
        for (int v = 0; v < 12; ++v) {
            unsigned sca0 = *(const unsigned*)(SaT + ((size_t)(24 + v) * M + rA[0]) * 4);
            unsigned sca1 = *(const unsigned*)(SaT + ((size_t)(24 + v) * M + rA[1]) * 4);
            unsigned scb0 = *(const unsigned*)(SbT + ((size_t)(24 + v) * N + cB[0]) * 4);
            unsigned scb1 = *(const unsigned*)(SbT + ((size_t)(24 + v) * N + cB[1]) * 4);
            intx8 af[2], bfr[2];
            #pragma unroll
            for (int i = 0; i < 2; i++) {
                const unsigned char* p = A6 + ((size_t)(2 * v + lh) * M + rA[i]) * 24;
                int2 u0 = *(const int2*)(p), u1 = *(const int2*)(p + 8), u2 = *(const int2*)(p + 16);
                af[i] = (intx8){ u0.x, u0.y, u1.x, u1.y, u2.x, u2.y, 0, 0 };
            }
            #pragma unroll
            for (int j = 0; j < 2; j++) {
                const unsigned char* p = B6 + ((size_t)(2 * v + lh) * N + cB[j]) * 24;
                int2 u0 = *(const int2*)(p), u1 = *(const int2*)(p + 8), u2 = *(const int2*)(p + 16);
                bfr[j] = (intx8){ u0.x, u0.y, u1.x, u1.y, u2.x, u2.y, 0, 0 };
            }
            int sh = 8 * lh;
            int sa[2] = { (int)((sca0 >> sh) & 255), (int)((sca1 >> sh) & 255) };
            int sb[2] = { (int)((scb0 >> sh) & 255), (int)((scb1 >> sh) & 255) };
            #pragma unroll
            for (int i = 0; i < 2; i++)
                #pragma unroll
                for (int j = 0; j < 2; j++)
                    acc[i][j] = __builtin_amdgcn_mfma_scale_f32_32x32x64_f8f6f4(
                        af[i], bfr[j], acc[i][j], 3, 3, 0, sa[i], 0, sb[j]);
        }
    }

    // ================= fp8 as bf16: 16 steps of K=16 =================
    {
        #pragma unroll 2
        for (int q = 0; q < 16; ++q) {
            short8 af[2], bfr[2];
            #pragma unroll
            for (int i = 0; i < 2; i++)
                af[i] = *(const short8*)(A8 + ((size_t)(2 * q + lh) * M + rA[i]) * 8);
            #pragma unroll
            for (int j = 0; j < 2; j++)
                bfr[j] = *(const short8*)(B8 + ((size_t)(2 * q + lh) * N + cB[j]) * 8);
            #pragma unroll
            for (int i = 0; i < 2; i++)
                #pragma unroll
                for (int j = 0; j < 2; j++)
                    acc[i][j] = __builtin_amdgcn_mfma_f32_32x32x16_bf16(af[i], bfr[j], acc[i][j], 0, 0, 0);
        }
    }

    // epilogue: 32x32 C/D layout col=lane&31, row=(r&3)+8*(r>>2)+4*lh (m74/m101-verified)
    #pragma unroll
    for (int i = 0; i < 2; i++)
        #pragma unroll
        for (int j = 0; j < 2; j++) {
            int col = bn * 128 + wn + j * 32 + lr;
            float bv = bias[col];
            #pragma unroll
            for (int r = 0; r < 16; r++) {
                int row = bm * 128 + wm + i * 32 + (r & 3) + 8 * (r >> 2) + 4 * lh;
                C[(size_t)row * N + col] = acc[i][j][r] + bv;
            }
        }
}

extern "C" void kernel_launch(void* const* d_in, const int* in_sizes, int n_in,
                              void* d_out, int out_size, void* d_ws, size_t ws_size,
                              hipStream_t stream) {
    const int* AN   = (const int*)d_in[0];
    const int* ASs  = (const int*)d_in[1];
    const int* AO   = (const int*)d_in[2];
    const int* SFAN = (const int*)d_in[3];
    const int* SFAS = (const int*)d_in[4];
    const int* SFAO = (const int*)d_in[5];
    const int* BN   = (const int*)d_in[6];
    const int* BS   = (const int*)d_in[7];
    const int* BO   = (const int*)d_in[8];
    const int* SFBN = (const int*)d_in[9];
    const int* SFBS = (const int*)d_in[10];
    const int* SFBO = (const int*)d_in[11];
    const float* bias = (const float*)d_in[12];

    int M = in_sizes[0] / 1536;
    int N = in_sizes[6] / 1536;

    unsigned char* ws = (unsigned char*)d_ws;
    size_t o = 0;
    unsigned char*  A4c = ws + o;                    o += (size_t)M * 1536;
    unsigned char*  B4c = ws + o;                    o += (size_t)N * 1536;
    unsigned char*  A6c = ws + o;                    o += (size_t)M * 576;
    unsigned char*  B6c = ws + o;                    o += (size_t)N * 576;
    unsigned short* A8d = (unsigned short*)(ws + o); o += (size_t)M * 512;
    unsigned short* B8d = (unsigned short*)(ws + o); o += (size_t)N * 512;
    unsigned char*  SaT = ws + o;                    o += (size_t)36 * M * 4;
    unsigned char*  SbT = ws + o;                    o += (size_t)36 * N * 4;

    int TA = M * 188, TB = N * 188;
    pack_side<<<(TA + 255) / 256, 256, 0, stream>>>(AN, ASs, AO, SFAN, SFAS, SFAO,
                                                    A4c, A6c, A8d, SaT, M);
    pack_side<<<(TB + 255) / 256, 256, 0, stream>>>(BN, BS, BO, SFBN, SFBS, SFBO,
                                                    B4c, B6c, B8d, SbT, N);

    dim3 grid(N / 128, M / 128);
    gemm_mx<<<grid, 256, 0, stream>>>(A4c, B4c, A6c, B6c, A8d, B8d,
                                      SaT, SbT, bias, (float*)d_out, M, N);
}